// Round 5
// baseline (358.637 us; speedup 1.0000x reference)
//
#include <hip/hip_runtime.h>
#include <math.h>

#define L_SEQ   2048
#define DLLM    768
#define E_DIM   64
#define NSLICE  16
#define EPSV    1e-5f

typedef _Float16 f16;
typedef _Float16 f16x8 __attribute__((ext_vector_type(8)));
typedef _Float16 f16x4 __attribute__((ext_vector_type(4)));
typedef float    f32x4 __attribute__((ext_vector_type(4)));

// ---------------------------------------------------------------------------
// prep: Wt16[192][768] = [Wq^T * 0.125 | Wk^T | Wv^T] fp16 ; bias[192] fp32
// ---------------------------------------------------------------------------
__global__ __launch_bounds__(256)
void prep_kernel(const float* __restrict__ Wq, const float* __restrict__ bq,
                 const float* __restrict__ Wk, const float* __restrict__ bk,
                 const float* __restrict__ Wv, const float* __restrict__ bv,
                 f16* __restrict__ Wt, float* __restrict__ bias)
{
    int b = blockIdx.x;
    if (b < 192) {
        int sel = b >> 6, c = b & 63;
        const float* W = (sel == 0) ? Wq : (sel == 1) ? Wk : Wv;
        float s = (sel == 0) ? 0.125f : 1.0f;
        for (int kd = threadIdx.x; kd < DLLM; kd += 256)
            Wt[b * DLLM + kd] = (f16)(W[kd * 64 + c] * s);
    } else {
        int t = threadIdx.x;
        if (t < 192) {
            int sel = t >> 6, c = t & 63;
            const float* bb = (sel == 0) ? bq : (sel == 1) ? bk : bv;
            bias[t] = bb[c] * ((sel == 0) ? 0.125f : 1.0f);
        }
    }
}

// ---------------------------------------------------------------------------
// proj: streaming MFMA GEMM, no LDS/barriers. Wave tile 16 rows x 96 cols;
// 4096 waves (1024 blocks) -> 16 waves/CU for TLP. A (info, HBM) prefetched
// one k-step ahead in registers; B (Wt, L2-hot) loaded in-iter.
// q,k stored [row][64]; V stored transposed: vT[slice][64][2048].
// ---------------------------------------------------------------------------
__global__ __launch_bounds__(256)
void proj_mfma(const float* __restrict__ info, const f16* __restrict__ Wt,
               const float* __restrict__ bias,
               f16* __restrict__ q16, f16* __restrict__ k16, f16* __restrict__ vT)
{
    const int tid = threadIdx.x;
    const int l   = tid & 63;
    const int wid = tid >> 6;
    const int l15 = l & 15, lg = l >> 4;
    const int w   = blockIdx.x * 4 + wid;   // 0..4095
    const int rt  = w >> 1;                 // 0..2047
    const int ch  = w & 1;
    const int r0  = rt * 16;
    const int n0  = ch * 96;

    f32x4 acc[6];
    #pragma unroll
    for (int ni = 0; ni < 6; ++ni) acc[ni] = (f32x4)(0.0f);

    const float* arow = info + (size_t)(r0 + l15) * DLLM + lg * 8;
    const f16* bbase[6];
    #pragma unroll
    for (int ni = 0; ni < 6; ++ni)
        bbase[ni] = Wt + (size_t)(n0 + ni * 16 + l15) * DLLM + lg * 8;

    float4 alo[2][2], ahi[2][2];   // [buf][kf]
    #pragma unroll
    for (int kf = 0; kf < 2; ++kf) {
        alo[0][kf] = *reinterpret_cast<const float4*>(arow + kf * 32);
        ahi[0][kf] = *reinterpret_cast<const float4*>(arow + kf * 32 + 4);
    }

    #pragma unroll
    for (int ks = 0; ks < 12; ++ks) {
        const int cur = ks & 1, nxt = cur ^ 1;
        const int k0 = ks * 64;
        const int kn = (ks < 11) ? (k0 + 64) : 0;   // wrap-clamp, unused data
        // prefetch next A k-step
        #pragma unroll
        for (int kf = 0; kf < 2; ++kf) {
            alo[nxt][kf] = *reinterpret_cast<const float4*>(arow + kn + kf * 32);
            ahi[nxt][kf] = *reinterpret_cast<const float4*>(arow + kn + kf * 32 + 4);
        }
        // cvt current A
        f16x8 af[2];
        #pragma unroll
        for (int kf = 0; kf < 2; ++kf) {
            float4 lo = alo[cur][kf], hi = ahi[cur][kf];
            f16x8 h;
            h[0] = (f16)lo.x; h[1] = (f16)lo.y; h[2] = (f16)lo.z; h[3] = (f16)lo.w;
            h[4] = (f16)hi.x; h[5] = (f16)hi.y; h[6] = (f16)hi.z; h[7] = (f16)hi.w;
            af[kf] = h;
        }
        // B from L2 + MFMA
        #pragma unroll
        for (int kf = 0; kf < 2; ++kf)
            #pragma unroll
            for (int ni = 0; ni < 6; ++ni) {
                f16x8 bf = *reinterpret_cast<const f16x8*>(bbase[ni] + k0 + kf * 32);
                acc[ni] = __builtin_amdgcn_mfma_f32_16x16x32_f16(af[kf], bf, acc[ni], 0, 0, 0);
            }
    }

    // epilogue: + bias, scatter
    #pragma unroll
    for (int ni = 0; ni < 6; ++ni) {
        const int nb  = n0 + ni * 16;        // uniform per ni
        const int n   = nb + l15;
        const int sel = nb >> 6;             // 0=q 1=k 2=v
        const int cc  = (nb & 63) + l15;
        const float bcol = bias[n];
        if (sel < 2) {
            f16* dst = (sel == 0) ? q16 : k16;
            #pragma unroll
            for (int rr = 0; rr < 4; ++rr) {
                int r = r0 + lg * 4 + rr;
                dst[(size_t)r * E_DIM + cc] = (f16)(acc[ni][rr] + bcol);
            }
        } else {
            int rb    = r0 + lg * 4;
            int slice = rb >> 11;
            int lloc  = rb & 2047;
            f16x4 v4;
            #pragma unroll
            for (int rr = 0; rr < 4; ++rr) v4[rr] = (f16)(acc[ni][rr] + bcol);
            *reinterpret_cast<f16x4*>(
                vT + (size_t)slice * E_DIM * L_SEQ + (size_t)cc * L_SEQ + lloc) = v4;
        }
    }
}

// ---------------------------------------------------------------------------
// attn: barrier-free flash attention, swapped QK^T + O^T = V^T P^T.
// Register software pipeline: K frags double-buffered across chunks,
// V frags issued at chunk start (land under QK^T + softmax).
// P bounced via wave-private LDS slab (no __syncthreads in kernel).
// ---------------------------------------------------------------------------
#define PSTRD 72   // f16 units; 144 B rows (16B aligned)

#define LOAD_K(DST, KV)                                                        \
    _Pragma("unroll") for (int ni = 0; ni < 4; ++ni)                           \
        _Pragma("unroll") for (int kf = 0; kf < 2; ++kf)                       \
            DST[ni][kf] = *reinterpret_cast<const f16x8*>(                     \
                kp + (size_t)((KV) + ni * 16 + l15) * E_DIM + kf * 32 + lg * 8);

#define LOAD_V(DST, KV)                                                        \
    _Pragma("unroll") for (int ei = 0; ei < 4; ++ei)                           \
        _Pragma("unroll") for (int kf = 0; kf < 2; ++kf)                       \
            DST[ei][kf] = *reinterpret_cast<const f16x8*>(                     \
                vp + (size_t)(ei * 16 + l15) * L_SEQ + (KV) + kf * 32 + lg * 8);

#define ATTN_CHUNK(KB, VB)                                                     \
    {                                                                          \
        f32x4 s[4];                                                            \
        _Pragma("unroll") for (int ni = 0; ni < 4; ++ni) s[ni] = (f32x4)(0.0f);\
        _Pragma("unroll") for (int kf = 0; kf < 2; ++kf)                       \
            _Pragma("unroll") for (int ni = 0; ni < 4; ++ni)                   \
                s[ni] = __builtin_amdgcn_mfma_f32_16x16x32_f16(                \
                    KB[ni][kf], qf[kf], s[ni], 0, 0, 0);                       \
        float mx = -1e30f;                                                     \
        _Pragma("unroll") for (int ni = 0; ni < 4; ++ni)                       \
            _Pragma("unroll") for (int r = 0; r < 4; ++r)                      \
                mx = fmaxf(mx, s[ni][r]);                                      \
        mx = fmaxf(mx, __shfl_xor(mx, 16));                                    \
        mx = fmaxf(mx, __shfl_xor(mx, 32));                                    \
        float Mn  = fmaxf(M, mx);                                              \
        float fsc = __expf(M - Mn);                                            \
        M = Mn;                                                                \
        float psum = 0.f;                                                      \
        _Pragma("unroll") for (int ni = 0; ni < 4; ++ni) {                     \
            f16x4 p4;                                                          \
            _Pragma("unroll") for (int r = 0; r < 4; ++r) {                    \
                float p = __expf(s[ni][r] - Mn);                               \
                psum += p; p4[r] = (f16)p;                                     \
            }                                                                  \
            *reinterpret_cast<f16x4*>(&P[l15 * PSTRD + ni * 16 + lg * 4]) = p4;\
        }                                                                      \
        Lr = Lr * fsc + psum;                                                  \
        _Pragma("unroll") for (int ei = 0; ei < 4; ++ei) {                     \
            oacc[ei][0] *= fsc; oacc[ei][1] *= fsc;                            \
            oacc[ei][2] *= fsc; oacc[ei][3] *= fsc;                            \
        }                                                                      \
        _Pragma("unroll") for (int kf = 0; kf < 2; ++kf) {                     \
            f16x8 pa = *reinterpret_cast<const f16x8*>(                        \
                &P[l15 * PSTRD + kf * 32 + lg * 8]);                           \
            _Pragma("unroll") for (int ei = 0; ei < 4; ++ei)                   \
                oacc[ei] = __builtin_amdgcn_mfma_f32_16x16x32_f16(             \
                    VB[ei][kf], pa, oacc[ei], 0, 0, 0);                        \
        }                                                                      \
    }

__global__ __launch_bounds__(256)
void attn_mfma(const f16* __restrict__ q16, const f16* __restrict__ k16,
               const f16* __restrict__ vT, float* __restrict__ att)
{
    __shared__ f16 Pl[4 * 16 * PSTRD];   // 9216 B, wave-private slabs

    const int tid = threadIdx.x;
    const int l   = tid & 63;
    const int wid = tid >> 6;
    const int l15 = l & 15, lg = l >> 4;
    const int slice = blockIdx.y;
    const int q0 = blockIdx.x * 64 + wid * 16;
    const f16* qp = q16 + (size_t)slice * L_SEQ * E_DIM;
    const f16* kp = k16 + (size_t)slice * L_SEQ * E_DIM;
    const f16* vp = vT  + (size_t)slice * E_DIM * L_SEQ;
    f16* P = &Pl[wid * 16 * PSTRD];

    // Q fragment (B-operand), q pre-scaled by 1/8
    f16x8 qf[2];
    #pragma unroll
    for (int kf = 0; kf < 2; ++kf)
        qf[kf] = *reinterpret_cast<const f16x8*>(
            qp + (size_t)(q0 + l15) * E_DIM + kf * 32 + lg * 8);

    f32x4 oacc[4];
    #pragma unroll
    for (int ei = 0; ei < 4; ++ei) oacc[ei] = (f32x4)(0.0f);
    float M = -1e30f, Lr = 0.f;

    f16x8 kbA[4][2], kbB[4][2], vb[4][2];
    LOAD_K(kbA, 0)

    for (int kv0 = 0; kv0 < L_SEQ; kv0 += 128) {
        // phase A: compute chunk kv0 from kbA; prefetch K for kv0+64 into kbB
        {
            LOAD_V(vb, kv0)                       // lands under QK^T+softmax
            const int nx = kv0 + 64;
            LOAD_K(kbB, nx)
            ATTN_CHUNK(kbA, vb)
        }
        // phase B: compute chunk kv0+64 from kbB; prefetch K for kv0+128
        {
            LOAD_V(vb, kv0 + 64)
            const int nx = (kv0 + 128) & (L_SEQ - 1);   // wrap-clamp on last
            LOAD_K(kbA, nx)
            ATTN_CHUNK(kbB, vb)
        }
    }

    // finalize: row sum across the 4 lg copies, divide, store O (fp32)
    float lt = Lr;
    lt += __shfl_xor(lt, 16);
    lt += __shfl_xor(lt, 32);
    float inv = 1.f / lt;
    size_t row = (size_t)slice * L_SEQ + q0 + l15;
    #pragma unroll
    for (int ei = 0; ei < 4; ++ei) {
        float4 o;
        o.x = oacc[ei][0] * inv; o.y = oacc[ei][1] * inv;
        o.z = oacc[ei][2] * inv; o.w = oacc[ei][3] * inv;
        *reinterpret_cast<float4*>(att + row * E_DIM + ei * 16 + lg * 4) = o;
    }
}

// ---------------------------------------------------------------------------
// InstanceNorm: per-block partial sums (no atomics, no init), then apply
// ---------------------------------------------------------------------------
__global__ __launch_bounds__(256)
void stats_kernel(const float* __restrict__ att, float* __restrict__ parts)
{
    const int slice = blockIdx.x >> 4;
    const int part  = blockIdx.x & 15;
    const int tid = threadIdx.x;
    const size_t base = (size_t)slice * L_SEQ * E_DIM + (size_t)part * 8192;
    float s = 0.f, sq = 0.f;
    #pragma unroll
    for (int it = 0; it < 8; ++it) {
        float4 v = *reinterpret_cast<const float4*>(att + base + (size_t)(it * 256 + tid) * 4);
        s  += v.x + v.y + v.z + v.w;
        sq += v.x * v.x + v.y * v.y + v.z * v.z + v.w * v.w;
    }
    for (int m = 1; m < 64; m <<= 1) {
        s  += __shfl_xor(s,  m);
        sq += __shfl_xor(sq, m);
    }
    __shared__ float red[8];
    const int wid = tid >> 6;
    if ((tid & 63) == 0) { red[wid * 2] = s; red[wid * 2 + 1] = sq; }
    __syncthreads();
    if (tid == 0) {
        parts[slice * 32 + part * 2]     = red[0] + red[2] + red[4] + red[6];
        parts[slice * 32 + part * 2 + 1] = red[1] + red[3] + red[5] + red[7];
    }
}

__global__ __launch_bounds__(256)
void apply_kernel(float* __restrict__ att, const float* __restrict__ parts)
{
    const int i4 = blockIdx.x * 256 + threadIdx.x;
    const size_t fl = (size_t)i4 * 4;
    const int slice = (int)(fl >> 17);
    float S = 0.f, SQ = 0.f;
    #pragma unroll
    for (int p = 0; p < 16; ++p) {
        S  += parts[slice * 32 + p * 2];
        SQ += parts[slice * 32 + p * 2 + 1];
    }
    const float N = (float)(L_SEQ * E_DIM);
    float mean = S / N;
    float var  = SQ / N - mean * mean;
    float inv  = rsqrtf(var + EPSV);
    float4 v = *reinterpret_cast<const float4*>(att + fl);
    float4 o;
    o.x = (v.x - mean) * inv;
    o.y = (v.y - mean) * inv;
    o.z = (v.z - mean) * inv;
    o.w = (v.w - mean) * inv;
    *reinterpret_cast<float4*>(att + fl) = o;
}

// ---------------------------------------------------------------------------
extern "C" void kernel_launch(void* const* d_in, const int* in_sizes, int n_in,
                              void* d_out, int out_size, void* d_ws, size_t ws_size,
                              hipStream_t stream)
{
    const float* info = (const float*)d_in[0];
    const float* Wq   = (const float*)d_in[1];
    const float* bq   = (const float*)d_in[2];
    const float* Wk   = (const float*)d_in[3];
    const float* bk   = (const float*)d_in[4];
    const float* Wv   = (const float*)d_in[5];
    const float* bv   = (const float*)d_in[6];

    // Workspace footprint: 13 MB (known-safe)
    char* ws = (char*)d_ws;
    f16*   Wt    = (f16*)(ws);                       // 294912 B
    float* bias  = (float*)(ws + 294912);            // 768 B
    float* parts = (float*)(ws + 295936);            // 2048 B
    f16*   q16   = (f16*)(ws + 1048576);             // 4 MB
    f16*   k16   = (f16*)(ws + 5242880);             // 4 MB
    f16*   vT    = (f16*)(ws + 9437184);             // 4 MB (end 13 MB)
    float* att   = (float*)d_out;

    prep_kernel<<<193, 256, 0, stream>>>(Wq, bq, Wk, bk, Wv, bv, Wt, bias);
    proj_mfma<<<1024, 256, 0, stream>>>(info, Wt, bias, q16, k16, vT);
    attn_mfma<<<dim3(L_SEQ / 64, NSLICE), 256, 0, stream>>>(q16, k16, vT, att);
    stats_kernel<<<256, 256, 0, stream>>>(att, parts);
    apply_kernel<<<2048, 256, 0, stream>>>(att, parts);
}

// Round 7
// 222.338 us; speedup vs baseline: 1.6130x; 1.6130x over previous
//
#include <hip/hip_runtime.h>
#include <math.h>

#define L_SEQ   2048
#define DLLM    768
#define E_DIM   64
#define NSLICE  16
#define EPSV    1e-5f
#define LSTR    72   // padded LDS row stride (f16 units): 144 B, hits b128 bank floor

typedef _Float16 f16;
typedef _Float16 f16x8 __attribute__((ext_vector_type(8)));
typedef _Float16 f16x4 __attribute__((ext_vector_type(4)));
typedef float    f32x4 __attribute__((ext_vector_type(4)));

// ---------------------------------------------------------------------------
// prep: Wt16[192][768] = [Wq^T * 0.125 | Wk^T | Wv^T] fp16 ; bias[192] fp32
// ---------------------------------------------------------------------------
__global__ __launch_bounds__(256)
void prep_kernel(const float* __restrict__ Wq, const float* __restrict__ bq,
                 const float* __restrict__ Wk, const float* __restrict__ bk,
                 const float* __restrict__ Wv, const float* __restrict__ bv,
                 f16* __restrict__ Wt, float* __restrict__ bias)
{
    int b = blockIdx.x;
    if (b < 192) {
        int sel = b >> 6, c = b & 63;
        const float* W = (sel == 0) ? Wq : (sel == 1) ? Wk : Wv;
        float s = (sel == 0) ? 0.125f : 1.0f;
        for (int kd = threadIdx.x; kd < DLLM; kd += 256)
            Wt[b * DLLM + kd] = (f16)(W[kd * 64 + c] * s);
    } else {
        int t = threadIdx.x;
        if (t < 192) {
            int sel = t >> 6, c = t & 63;
            const float* bb = (sel == 0) ? bq : (sel == 1) ? bk : bv;
            bias[t] = bb[c] * ((sel == 0) ? 0.125f : 1.0f);
        }
    }
}

// ---------------------------------------------------------------------------
// proj: LDS-staged MFMA GEMM. Tile 64 rows x 192 cols, BK=64, 4 waves (2x2),
// wave tile 32x96. Double-buffered LDS; reg-staged (fp32->f16 cvt in stage);
// global loads for step t+1 issued before compute of step t.
// q,k stored [row][64]; V stored transposed: vT[slice][64][2048].
// ---------------------------------------------------------------------------
__global__ __launch_bounds__(256)
void proj_mfma(const float* __restrict__ info, const f16* __restrict__ Wt,
               const float* __restrict__ bias,
               f16* __restrict__ q16, f16* __restrict__ k16, f16* __restrict__ vT)
{
    __shared__ f16 As[2][64 * LSTR];    // 2 x  9216 B
    __shared__ f16 Bs[2][192 * LSTR];   // 2 x 27648 B   (total 73728 B)

    const int tid = threadIdx.x;
    const int l   = tid & 63;
    const int wid = tid >> 6;
    const int l15 = l & 15, lg = l >> 4;
    const int wm  = (wid >> 1) * 32;
    const int wn  = (wid & 1) * 96;
    const int r0  = blockIdx.x * 64;
    const int srow = tid >> 3;   // 0..31
    const int sc8  = tid & 7;    // 16B column group

    f32x4 acc[2][6];
    #pragma unroll
    for (int mi = 0; mi < 2; ++mi)
        #pragma unroll
        for (int ni = 0; ni < 6; ++ni) acc[mi][ni] = (f32x4)(0.0f);

    float4 fa[2][2];   // A stage: 2 rows-of-8-floats per thread
    f16x8  gb[6];      // B stage: 6 x 16B per thread

    // ---- prologue: load k-step 0, write LDS[0]
    #pragma unroll
    for (int u = 0; u < 2; ++u) {
        const float* src = info + (size_t)(r0 + u * 32 + srow) * DLLM + sc8 * 8;
        fa[u][0] = *reinterpret_cast<const float4*>(src);
        fa[u][1] = *reinterpret_cast<const float4*>(src + 4);
    }
    #pragma unroll
    for (int u = 0; u < 6; ++u)
        gb[u] = *reinterpret_cast<const f16x8*>(
            Wt + (size_t)(u * 32 + srow) * DLLM + sc8 * 8);

    #pragma unroll
    for (int u = 0; u < 2; ++u) {
        f16x8 h;
        #pragma unroll
        for (int j = 0; j < 4; ++j) {
            h[j]     = (f16)(&fa[u][0].x)[j];
            h[j + 4] = (f16)(&fa[u][1].x)[j];
        }
        *reinterpret_cast<f16x8*>(&As[0][(u * 32 + srow) * LSTR + sc8 * 8]) = h;
    }
    #pragma unroll
    for (int u = 0; u < 6; ++u)
        *reinterpret_cast<f16x8*>(&Bs[0][(u * 32 + srow) * LSTR + sc8 * 8]) = gb[u];
    __syncthreads();

    // ---- main loop
    for (int ks = 0; ks < 12; ++ks) {
        const int cur = ks & 1;
        const int kn  = (ks + 1) * 64;
        if (ks < 11) {
            #pragma unroll
            for (int u = 0; u < 2; ++u) {
                const float* src = info + (size_t)(r0 + u * 32 + srow) * DLLM + kn + sc8 * 8;
                fa[u][0] = *reinterpret_cast<const float4*>(src);
                fa[u][1] = *reinterpret_cast<const float4*>(src + 4);
            }
            #pragma unroll
            for (int u = 0; u < 6; ++u)
                gb[u] = *reinterpret_cast<const f16x8*>(
                    Wt + (size_t)(u * 32 + srow) * DLLM + kn + sc8 * 8);
        }

        const f16* Ac = As[cur];
        const f16* Bc = Bs[cur];
        #pragma unroll
        for (int kf = 0; kf < 2; ++kf) {
            f16x8 af[2], bf[6];
            #pragma unroll
            for (int mi = 0; mi < 2; ++mi)
                af[mi] = *reinterpret_cast<const f16x8*>(
                    &Ac[(wm + mi * 16 + l15) * LSTR + kf * 32 + lg * 8]);
            #pragma unroll
            for (int ni = 0; ni < 6; ++ni)
                bf[ni] = *reinterpret_cast<const f16x8*>(
                    &Bc[(wn + ni * 16 + l15) * LSTR + kf * 32 + lg * 8]);
            #pragma unroll
            for (int mi = 0; mi < 2; ++mi)
                #pragma unroll
                for (int ni = 0; ni < 6; ++ni)
                    acc[mi][ni] = __builtin_amdgcn_mfma_f32_16x16x32_f16(
                        af[mi], bf[ni], acc[mi][ni], 0, 0, 0);
        }

        if (ks < 11) {
            f16* An = As[cur ^ 1];
            f16* Bn = Bs[cur ^ 1];
            #pragma unroll
            for (int u = 0; u < 2; ++u) {
                f16x8 h;
                #pragma unroll
                for (int j = 0; j < 4; ++j) {
                    h[j]     = (f16)(&fa[u][0].x)[j];
                    h[j + 4] = (f16)(&fa[u][1].x)[j];
                }
                *reinterpret_cast<f16x8*>(&An[(u * 32 + srow) * LSTR + sc8 * 8]) = h;
            }
            #pragma unroll
            for (int u = 0; u < 6; ++u)
                *reinterpret_cast<f16x8*>(&Bn[(u * 32 + srow) * LSTR + sc8 * 8]) = gb[u];
        }
        __syncthreads();
    }

    // ---- epilogue: + bias, scatter to q / k / vT
    #pragma unroll
    for (int ni = 0; ni < 6; ++ni) {
        const int nb  = wn + ni * 16;      // uniform per ni
        const int n   = nb + l15;
        const int sel = nb >> 6;           // 0=q 1=k 2=v
        const int cc  = (nb & 63) + l15;
        const float bcol = bias[n];
        if (sel < 2) {
            f16* dst = (sel == 0) ? q16 : k16;
            #pragma unroll
            for (int mi = 0; mi < 2; ++mi)
                #pragma unroll
                for (int rr = 0; rr < 4; ++rr) {
                    int r = r0 + wm + mi * 16 + lg * 4 + rr;
                    dst[(size_t)r * E_DIM + cc] = (f16)(acc[mi][ni][rr] + bcol);
                }
        } else {
            #pragma unroll
            for (int mi = 0; mi < 2; ++mi) {
                int rb    = r0 + wm + mi * 16 + lg * 4;
                int slice = rb >> 11;
                int lloc  = rb & 2047;
                f16x4 v4;
                #pragma unroll
                for (int rr = 0; rr < 4; ++rr) v4[rr] = (f16)(acc[mi][ni][rr] + bcol);
                *reinterpret_cast<f16x4*>(
                    vT + (size_t)slice * E_DIM * L_SEQ + (size_t)cc * L_SEQ + lloc) = v4;
            }
        }
    }
}

// ---------------------------------------------------------------------------
// attn: flash attention, swapped QK^T + O^T = V^T P^T. 4 waves x 16 q-rows.
// K and V^T chunks (64 kv) double-buffered in LDS, reg-staged with coalesced
// global loads issued before the previous chunk's compute. One barrier/chunk.
// P bounced via wave-private LDS slab. Softmax lane-local per q-row.
// ---------------------------------------------------------------------------
__global__ __launch_bounds__(256)
void attn_mfma(const f16* __restrict__ q16, const f16* __restrict__ k16,
               const f16* __restrict__ vT, float* __restrict__ att)
{
    __shared__ f16 Ks[2][64 * LSTR];   // 2 x 9216 B
    __shared__ f16 Vs[2][64 * LSTR];   // 2 x 9216 B
    __shared__ f16 Pl[4 * 16 * LSTR];  // 9216 B   (total 46080 B)

    const int tid = threadIdx.x;
    const int l   = tid & 63;
    const int wid = tid >> 6;
    const int l15 = l & 15, lg = l >> 4;
    const int slice = blockIdx.y;
    const int q0 = blockIdx.x * 64 + wid * 16;
    const f16* qp = q16 + (size_t)slice * L_SEQ * E_DIM;
    const f16* kp = k16 + (size_t)slice * L_SEQ * E_DIM;
    const f16* vp = vT  + (size_t)slice * E_DIM * L_SEQ;
    f16* P = &Pl[wid * 16 * LSTR];
    const int srow = tid >> 3;   // 0..31
    const int sc8  = tid & 7;

    // Q fragment (B-operand), q pre-scaled by 1/8
    f16x8 qf[2];
    #pragma unroll
    for (int kf = 0; kf < 2; ++kf)
        qf[kf] = *reinterpret_cast<const f16x8*>(
            qp + (size_t)(q0 + l15) * E_DIM + kf * 32 + lg * 8);

    f32x4 oacc[4];
    #pragma unroll
    for (int ei = 0; ei < 4; ++ei) oacc[ei] = (f32x4)(0.0f);
    float M = -1e30f, Lr = 0.f;

    f16x8 gk[2], gv[2];
    // prologue: stage chunk 0
    #pragma unroll
    for (int u = 0; u < 2; ++u) {
        int row = u * 32 + srow;
        gk[u] = *reinterpret_cast<const f16x8*>(kp + (size_t)row * E_DIM + sc8 * 8);
        gv[u] = *reinterpret_cast<const f16x8*>(vp + (size_t)row * L_SEQ + sc8 * 8);
    }
    #pragma unroll
    for (int u = 0; u < 2; ++u) {
        int row = u * 32 + srow;
        *reinterpret_cast<f16x8*>(&Ks[0][row * LSTR + sc8 * 8]) = gk[u];
        *reinterpret_cast<f16x8*>(&Vs[0][row * LSTR + sc8 * 8]) = gv[u];
    }
    __syncthreads();

    for (int ch = 0; ch < 32; ++ch) {
        const int cur = ch & 1;
        const int kvn = (ch + 1) * 64;
        if (ch < 31) {   // issue next-chunk loads; land under compute
            #pragma unroll
            for (int u = 0; u < 2; ++u) {
                int row = u * 32 + srow;
                gk[u] = *reinterpret_cast<const f16x8*>(
                    kp + (size_t)(kvn + row) * E_DIM + sc8 * 8);
                gv[u] = *reinterpret_cast<const f16x8*>(
                    vp + (size_t)row * L_SEQ + kvn + sc8 * 8);
            }
        }

        const f16* Kc = Ks[cur];
        const f16* Vc = Vs[cur];

        // S^T = K Q : lane holds S[q=l15][kv = ni*16 + lg*4 + r]
        f32x4 s[4];
        #pragma unroll
        for (int ni = 0; ni < 4; ++ni) s[ni] = (f32x4)(0.0f);
        #pragma unroll
        for (int kf = 0; kf < 2; ++kf)
            #pragma unroll
            for (int ni = 0; ni < 4; ++ni) {
                f16x8 kb = *reinterpret_cast<const f16x8*>(
                    &Kc[(ni * 16 + l15) * LSTR + kf * 32 + lg * 8]);
                s[ni] = __builtin_amdgcn_mfma_f32_16x16x32_f16(kb, qf[kf], s[ni], 0, 0, 0);
            }

        // online softmax, q-row lane-local (plus 2 cross-lane reduces)
        float mx = -1e30f;
        #pragma unroll
        for (int ni = 0; ni < 4; ++ni)
            #pragma unroll
            for (int r = 0; r < 4; ++r) mx = fmaxf(mx, s[ni][r]);
        mx = fmaxf(mx, __shfl_xor(mx, 16));
        mx = fmaxf(mx, __shfl_xor(mx, 32));
        float Mn  = fmaxf(M, mx);
        float fsc = __expf(M - Mn);
        M = Mn;
        float psum = 0.f;
        #pragma unroll
        for (int ni = 0; ni < 4; ++ni) {
            f16x4 p4;
            #pragma unroll
            for (int r = 0; r < 4; ++r) {
                float p = __expf(s[ni][r] - Mn);
                psum += p;
                p4[r] = (f16)p;
            }
            *reinterpret_cast<f16x4*>(&P[l15 * LSTR + ni * 16 + lg * 4]) = p4;
        }
        Lr = Lr * fsc + psum;
        #pragma unroll
        for (int ei = 0; ei < 4; ++ei) {
            oacc[ei][0] *= fsc; oacc[ei][1] *= fsc;
            oacc[ei][2] *= fsc; oacc[ei][3] *= fsc;
        }

        // O^T += V^T P^T
        #pragma unroll
        for (int kf = 0; kf < 2; ++kf) {
            f16x8 pa = *reinterpret_cast<const f16x8*>(
                &P[l15 * LSTR + kf * 32 + lg * 8]);
            #pragma unroll
            for (int ei = 0; ei < 4; ++ei) {
                f16x8 vb = *reinterpret_cast<const f16x8*>(
                    &Vc[(ei * 16 + l15) * LSTR + kf * 32 + lg * 8]);
                oacc[ei] = __builtin_amdgcn_mfma_f32_16x16x32_f16(vb, pa, oacc[ei], 0, 0, 0);
            }
        }

        if (ch < 31) {   // write staged regs into the other buffer
            f16* Kn = Ks[cur ^ 1];
            f16* Vn = Vs[cur ^ 1];
            #pragma unroll
            for (int u = 0; u < 2; ++u) {
                int row = u * 32 + srow;
                *reinterpret_cast<f16x8*>(&Kn[row * LSTR + sc8 * 8]) = gk[u];
                *reinterpret_cast<f16x8*>(&Vn[row * LSTR + sc8 * 8]) = gv[u];
            }
        }
        __syncthreads();
    }

    // finalize
    float lt = Lr;
    lt += __shfl_xor(lt, 16);
    lt += __shfl_xor(lt, 32);
    float inv = 1.f / lt;
    size_t row = (size_t)slice * L_SEQ + q0 + l15;
    #pragma unroll
    for (int ei = 0; ei < 4; ++ei) {
        float4 o;
        o.x = oacc[ei][0] * inv; o.y = oacc[ei][1] * inv;
        o.z = oacc[ei][2] * inv; o.w = oacc[ei][3] * inv;
        *reinterpret_cast<float4*>(att + row * E_DIM + ei * 16 + lg * 4) = o;
    }
}

// ---------------------------------------------------------------------------
// InstanceNorm: per-block partial sums (no atomics, no init), then apply
// ---------------------------------------------------------------------------
__global__ __launch_bounds__(256)
void stats_kernel(const float* __restrict__ att, float* __restrict__ parts)
{
    const int slice = blockIdx.x >> 4;
    const int part  = blockIdx.x & 15;
    const int tid = threadIdx.x;
    const size_t base = (size_t)slice * L_SEQ * E_DIM + (size_t)part * 8192;
    float s = 0.f, sq = 0.f;
    #pragma unroll
    for (int it = 0; it < 8; ++it) {
        float4 v = *reinterpret_cast<const float4*>(att + base + (size_t)(it * 256 + tid) * 4);
        s  += v.x + v.y + v.z + v.w;
        sq += v.x * v.x + v.y * v.y + v.z * v.z + v.w * v.w;
    }
    for (int m = 1; m < 64; m <<= 1) {
        s  += __shfl_xor(s,  m);
        sq += __shfl_xor(sq, m);
    }
    __shared__ float red[8];
    const int wid = tid >> 6;
    if ((tid & 63) == 0) { red[wid * 2] = s; red[wid * 2 + 1] = sq; }
    __syncthreads();
    if (tid == 0) {
        parts[slice * 32 + part * 2]     = red[0] + red[2] + red[4] + red[6];
        parts[slice * 32 + part * 2 + 1] = red[1] + red[3] + red[5] + red[7];
    }
}

__global__ __launch_bounds__(256)
void apply_kernel(float* __restrict__ att, const float* __restrict__ parts)
{
    const int i4 = blockIdx.x * 256 + threadIdx.x;
    const size_t fl = (size_t)i4 * 4;
    const int slice = (int)(fl >> 17);
    float S = 0.f, SQ = 0.f;
    #pragma unroll
    for (int p = 0; p < 16; ++p) {
        S  += parts[slice * 32 + p * 2];
        SQ += parts[slice * 32 + p * 2 + 1];
    }
    const float N = (float)(L_SEQ * E_DIM);
    float mean = S / N;
    float var  = SQ / N - mean * mean;
    float inv  = rsqrtf(var + EPSV);
    float4 v = *reinterpret_cast<const float4*>(att + fl);
    float4 o;
    o.x = (v.x - mean) * inv;
    o.y = (v.y - mean) * inv;
    o.z = (v.z - mean) * inv;
    o.w = (v.w - mean) * inv;
    *reinterpret_cast<float4*>(att + fl) = o;
}

// ---------------------------------------------------------------------------
extern "C" void kernel_launch(void* const* d_in, const int* in_sizes, int n_in,
                              void* d_out, int out_size, void* d_ws, size_t ws_size,
                              hipStream_t stream)
{
    const float* info = (const float*)d_in[0];
    const float* Wq   = (const float*)d_in[1];
    const float* bq   = (const float*)d_in[2];
    const float* Wk   = (const float*)d_in[3];
    const float* bk   = (const float*)d_in[4];
    const float* Wv   = (const float*)d_in[5];
    const float* bv   = (const float*)d_in[6];

    // Workspace footprint: 13 MB (known-safe)
    char* ws = (char*)d_ws;
    f16*   Wt    = (f16*)(ws);                       // 294912 B
    float* bias  = (float*)(ws + 294912);            // 768 B
    float* parts = (float*)(ws + 295936);            // 2048 B
    f16*   q16   = (f16*)(ws + 1048576);             // 4 MB
    f16*   k16   = (f16*)(ws + 5242880);             // 4 MB
    f16*   vT    = (f16*)(ws + 9437184);             // 4 MB (end 13 MB)
    float* att   = (float*)d_out;

    prep_kernel<<<193, 256, 0, stream>>>(Wq, bq, Wk, bk, Wv, bv, Wt, bias);
    proj_mfma<<<512, 256, 0, stream>>>(info, Wt, bias, q16, k16, vT);
    attn_mfma<<<dim3(L_SEQ / 64, NSLICE), 256, 0, stream>>>(q16, k16, vT, att);
    stats_kernel<<<256, 256, 0, stream>>>(att, parts);
    apply_kernel<<<2048, 256, 0, stream>>>(att, parts);
}

// Round 8
// 217.597 us; speedup vs baseline: 1.6482x; 1.0218x over previous
//
#include <hip/hip_runtime.h>
#include <math.h>

#define L_SEQ   2048
#define DLLM    768
#define E_DIM   64
#define NSLICE  16
#define EPSV    1e-5f
#define LSTR    72   // padded LDS row stride (f16 units): 144 B

typedef _Float16 f16;
typedef _Float16 f16x8 __attribute__((ext_vector_type(8)));
typedef _Float16 f16x4 __attribute__((ext_vector_type(4)));
typedef float    f32x4 __attribute__((ext_vector_type(4)));

// ---------------------------------------------------------------------------
// prep: Wt16[192][768] = [Wq^T * 0.125 | Wk^T | Wv^T] fp16 via LDS transpose.
// 36 blocks: mat = b/12, k0 = (b%12)*64. Coalesced reads AND writes.
// ---------------------------------------------------------------------------
__global__ __launch_bounds__(256)
void prep_kernel(const float* __restrict__ Wq, const float* __restrict__ bq,
                 const float* __restrict__ Wk, const float* __restrict__ bk,
                 const float* __restrict__ Wv, const float* __restrict__ bv,
                 f16* __restrict__ Wt, float* __restrict__ bias)
{
    __shared__ float tile[64][69];
    const int tid = threadIdx.x;
    const int mat = blockIdx.x / 12;
    const int k0  = (blockIdx.x % 12) * 64;
    const float* W = (mat == 0) ? Wq : (mat == 1) ? Wk : Wv;
    const float scale = (mat == 0) ? 0.125f : 1.0f;

    // load 64 k-rows x 64 cols, coalesced
    #pragma unroll
    for (int u = 0; u < 4; ++u) {
        int r  = u * 16 + (tid >> 4);
        int c4 = tid & 15;
        float4 v = *reinterpret_cast<const float4*>(W + (size_t)(k0 + r) * 64 + c4 * 4);
        tile[r][c4 * 4 + 0] = v.x;
        tile[r][c4 * 4 + 1] = v.y;
        tile[r][c4 * 4 + 2] = v.z;
        tile[r][c4 * 4 + 3] = v.w;
    }
    __syncthreads();

    // write transposed: Wt[(mat*64+c)*768 + k0 + k], f16, scaled
    #pragma unroll
    for (int p = 0; p < 2; ++p) {
        int c   = p * 32 + (tid >> 3);
        int sc8 = tid & 7;
        f16x8 h;
        #pragma unroll
        for (int j = 0; j < 8; ++j)
            h[j] = (f16)(tile[sc8 * 8 + j][c] * scale);
        *reinterpret_cast<f16x8*>(
            Wt + (size_t)(mat * 64 + c) * DLLM + k0 + sc8 * 8) = h;
    }

    if ((blockIdx.x % 12) == 0 && tid < 64) {
        const float* bb = (mat == 0) ? bq : (mat == 1) ? bk : bv;
        bias[mat * 64 + tid] = bb[tid] * scale;
    }
}

// ---------------------------------------------------------------------------
// proj: LDS-staged MFMA GEMM (UNCHANGED from round 7). Tile 64x192, BK=64,
// 4 waves (2x2), wave tile 32x96, double-buffered, reg-staged.
// ---------------------------------------------------------------------------
__global__ __launch_bounds__(256)
void proj_mfma(const float* __restrict__ info, const f16* __restrict__ Wt,
               const float* __restrict__ bias,
               f16* __restrict__ q16, f16* __restrict__ k16, f16* __restrict__ vT)
{
    __shared__ f16 As[2][64 * LSTR];
    __shared__ f16 Bs[2][192 * LSTR];

    const int tid = threadIdx.x;
    const int l   = tid & 63;
    const int wid = tid >> 6;
    const int l15 = l & 15, lg = l >> 4;
    const int wm  = (wid >> 1) * 32;
    const int wn  = (wid & 1) * 96;
    const int r0  = blockIdx.x * 64;
    const int srow = tid >> 3;
    const int sc8  = tid & 7;

    f32x4 acc[2][6];
    #pragma unroll
    for (int mi = 0; mi < 2; ++mi)
        #pragma unroll
        for (int ni = 0; ni < 6; ++ni) acc[mi][ni] = (f32x4)(0.0f);

    float4 fa[2][2];
    f16x8  gb[6];

    #pragma unroll
    for (int u = 0; u < 2; ++u) {
        const float* src = info + (size_t)(r0 + u * 32 + srow) * DLLM + sc8 * 8;
        fa[u][0] = *reinterpret_cast<const float4*>(src);
        fa[u][1] = *reinterpret_cast<const float4*>(src + 4);
    }
    #pragma unroll
    for (int u = 0; u < 6; ++u)
        gb[u] = *reinterpret_cast<const f16x8*>(
            Wt + (size_t)(u * 32 + srow) * DLLM + sc8 * 8);

    #pragma unroll
    for (int u = 0; u < 2; ++u) {
        f16x8 h;
        #pragma unroll
        for (int j = 0; j < 4; ++j) {
            h[j]     = (f16)(&fa[u][0].x)[j];
            h[j + 4] = (f16)(&fa[u][1].x)[j];
        }
        *reinterpret_cast<f16x8*>(&As[0][(u * 32 + srow) * LSTR + sc8 * 8]) = h;
    }
    #pragma unroll
    for (int u = 0; u < 6; ++u)
        *reinterpret_cast<f16x8*>(&Bs[0][(u * 32 + srow) * LSTR + sc8 * 8]) = gb[u];
    __syncthreads();

    for (int ks = 0; ks < 12; ++ks) {
        const int cur = ks & 1;
        const int kn  = (ks + 1) * 64;
        if (ks < 11) {
            #pragma unroll
            for (int u = 0; u < 2; ++u) {
                const float* src = info + (size_t)(r0 + u * 32 + srow) * DLLM + kn + sc8 * 8;
                fa[u][0] = *reinterpret_cast<const float4*>(src);
                fa[u][1] = *reinterpret_cast<const float4*>(src + 4);
            }
            #pragma unroll
            for (int u = 0; u < 6; ++u)
                gb[u] = *reinterpret_cast<const f16x8*>(
                    Wt + (size_t)(u * 32 + srow) * DLLM + kn + sc8 * 8);
        }

        const f16* Ac = As[cur];
        const f16* Bc = Bs[cur];
        #pragma unroll
        for (int kf = 0; kf < 2; ++kf) {
            f16x8 af[2], bf[6];
            #pragma unroll
            for (int mi = 0; mi < 2; ++mi)
                af[mi] = *reinterpret_cast<const f16x8*>(
                    &Ac[(wm + mi * 16 + l15) * LSTR + kf * 32 + lg * 8]);
            #pragma unroll
            for (int ni = 0; ni < 6; ++ni)
                bf[ni] = *reinterpret_cast<const f16x8*>(
                    &Bc[(wn + ni * 16 + l15) * LSTR + kf * 32 + lg * 8]);
            #pragma unroll
            for (int mi = 0; mi < 2; ++mi)
                #pragma unroll
                for (int ni = 0; ni < 6; ++ni)
                    acc[mi][ni] = __builtin_amdgcn_mfma_f32_16x16x32_f16(
                        af[mi], bf[ni], acc[mi][ni], 0, 0, 0);
        }

        if (ks < 11) {
            f16* An = As[cur ^ 1];
            f16* Bn = Bs[cur ^ 1];
            #pragma unroll
            for (int u = 0; u < 2; ++u) {
                f16x8 h;
                #pragma unroll
                for (int j = 0; j < 4; ++j) {
                    h[j]     = (f16)(&fa[u][0].x)[j];
                    h[j + 4] = (f16)(&fa[u][1].x)[j];
                }
                *reinterpret_cast<f16x8*>(&An[(u * 32 + srow) * LSTR + sc8 * 8]) = h;
            }
            #pragma unroll
            for (int u = 0; u < 6; ++u)
                *reinterpret_cast<f16x8*>(&Bn[(u * 32 + srow) * LSTR + sc8 * 8]) = gb[u];
        }
        __syncthreads();
    }

    #pragma unroll
    for (int ni = 0; ni < 6; ++ni) {
        const int nb  = wn + ni * 16;
        const int n   = nb + l15;
        const int sel = nb >> 6;
        const int cc  = (nb & 63) + l15;
        const float bcol = bias[n];
        if (sel < 2) {
            f16* dst = (sel == 0) ? q16 : k16;
            #pragma unroll
            for (int mi = 0; mi < 2; ++mi)
                #pragma unroll
                for (int rr = 0; rr < 4; ++rr) {
                    int r = r0 + wm + mi * 16 + lg * 4 + rr;
                    dst[(size_t)r * E_DIM + cc] = (f16)(acc[mi][ni][rr] + bcol);
                }
        } else {
            #pragma unroll
            for (int mi = 0; mi < 2; ++mi) {
                int rb    = r0 + wm + mi * 16 + lg * 4;
                int slice = rb >> 11;
                int lloc  = rb & 2047;
                f16x4 v4;
                #pragma unroll
                for (int rr = 0; rr < 4; ++rr) v4[rr] = (f16)(acc[mi][ni][rr] + bcol);
                *reinterpret_cast<f16x4*>(
                    vT + (size_t)slice * E_DIM * L_SEQ + (size_t)cc * L_SEQ + lloc) = v4;
            }
        }
    }
}

// ---------------------------------------------------------------------------
// attn: flash attention, 8 waves x 16 q-rows (QBLK=128), KVBLK=64.
// K/V^T double-buffered in LDS, shared by 8 waves (staging per q-row halved).
// setprio around MFMA clusters; defer-max rescale skip. One barrier/chunk.
// ---------------------------------------------------------------------------
__global__ __launch_bounds__(512, 4)
void attn_mfma(const f16* __restrict__ q16, const f16* __restrict__ k16,
               const f16* __restrict__ vT, float* __restrict__ att)
{
    __shared__ f16 Ks[2][64 * LSTR];   // 2 x 9216 B
    __shared__ f16 Vs[2][64 * LSTR];   // 2 x 9216 B
    __shared__ f16 Pl[8 * 16 * LSTR];  // 18432 B   (total 55296 B)

    const int tid = threadIdx.x;
    const int l   = tid & 63;
    const int wid = tid >> 6;          // 0..7
    const int l15 = l & 15, lg = l >> 4;
    const int slice = blockIdx.y;
    const int q0 = blockIdx.x * 128 + wid * 16;
    const f16* qp = q16 + (size_t)slice * L_SEQ * E_DIM;
    const f16* kp = k16 + (size_t)slice * L_SEQ * E_DIM;
    const f16* vp = vT  + (size_t)slice * E_DIM * L_SEQ;
    f16* P = &Pl[wid * 16 * LSTR];
    const int srow = tid >> 3;         // 0..63
    const int sc8  = tid & 7;

    f16x8 qf[2];
    #pragma unroll
    for (int kf = 0; kf < 2; ++kf)
        qf[kf] = *reinterpret_cast<const f16x8*>(
            qp + (size_t)(q0 + l15) * E_DIM + kf * 32 + lg * 8);

    f32x4 oacc[4];
    #pragma unroll
    for (int ei = 0; ei < 4; ++ei) oacc[ei] = (f32x4)(0.0f);
    float M = -1e30f, Lr = 0.f;

    f16x8 gk, gv;
    gk = *reinterpret_cast<const f16x8*>(kp + (size_t)srow * E_DIM + sc8 * 8);
    gv = *reinterpret_cast<const f16x8*>(vp + (size_t)srow * L_SEQ + sc8 * 8);
    *reinterpret_cast<f16x8*>(&Ks[0][srow * LSTR + sc8 * 8]) = gk;
    *reinterpret_cast<f16x8*>(&Vs[0][srow * LSTR + sc8 * 8]) = gv;
    __syncthreads();

    for (int ch = 0; ch < 32; ++ch) {
        const int cur = ch & 1;
        const int kvn = (ch + 1) * 64;
        if (ch < 31) {   // issue next-chunk loads; land under compute
            gk = *reinterpret_cast<const f16x8*>(
                kp + (size_t)(kvn + srow) * E_DIM + sc8 * 8);
            gv = *reinterpret_cast<const f16x8*>(
                vp + (size_t)srow * L_SEQ + kvn + sc8 * 8);
        }

        const f16* Kc = Ks[cur];
        const f16* Vc = Vs[cur];

        // S^T = K Q : lane holds S[q=l15][kv = ni*16 + lg*4 + r]
        f32x4 s[4];
        #pragma unroll
        for (int ni = 0; ni < 4; ++ni) s[ni] = (f32x4)(0.0f);
        __builtin_amdgcn_s_setprio(1);
        #pragma unroll
        for (int kf = 0; kf < 2; ++kf)
            #pragma unroll
            for (int ni = 0; ni < 4; ++ni) {
                f16x8 kb = *reinterpret_cast<const f16x8*>(
                    &Kc[(ni * 16 + l15) * LSTR + kf * 32 + lg * 8]);
                s[ni] = __builtin_amdgcn_mfma_f32_16x16x32_f16(kb, qf[kf], s[ni], 0, 0, 0);
            }
        __builtin_amdgcn_s_setprio(0);

        // online softmax, q-row lane-local; defer-max skip of O-rescale
        float mx = -1e30f;
        #pragma unroll
        for (int ni = 0; ni < 4; ++ni)
            #pragma unroll
            for (int r = 0; r < 4; ++r) mx = fmaxf(mx, s[ni][r]);
        mx = fmaxf(mx, __shfl_xor(mx, 16));
        mx = fmaxf(mx, __shfl_xor(mx, 32));
        if (!__all(mx <= M + 8.f)) {
            float Mn  = fmaxf(M, mx);
            float fsc = __expf(M - Mn);
            M = Mn;
            Lr *= fsc;
            #pragma unroll
            for (int ei = 0; ei < 4; ++ei) {
                oacc[ei][0] *= fsc; oacc[ei][1] *= fsc;
                oacc[ei][2] *= fsc; oacc[ei][3] *= fsc;
            }
        }
        float psum = 0.f;
        #pragma unroll
        for (int ni = 0; ni < 4; ++ni) {
            f16x4 p4;
            #pragma unroll
            for (int r = 0; r < 4; ++r) {
                float p = __expf(s[ni][r] - M);
                psum += p;
                p4[r] = (f16)p;
            }
            *reinterpret_cast<f16x4*>(&P[l15 * LSTR + ni * 16 + lg * 4]) = p4;
        }
        Lr += psum;

        // O^T += V^T P^T
        __builtin_amdgcn_s_setprio(1);
        #pragma unroll
        for (int kf = 0; kf < 2; ++kf) {
            f16x8 pa = *reinterpret_cast<const f16x8*>(
                &P[l15 * LSTR + kf * 32 + lg * 8]);
            #pragma unroll
            for (int ei = 0; ei < 4; ++ei) {
                f16x8 vb = *reinterpret_cast<const f16x8*>(
                    &Vc[(ei * 16 + l15) * LSTR + kf * 32 + lg * 8]);
                oacc[ei] = __builtin_amdgcn_mfma_f32_16x16x32_f16(vb, pa, oacc[ei], 0, 0, 0);
            }
        }
        __builtin_amdgcn_s_setprio(0);

        if (ch < 31) {
            f16* Kn = Ks[cur ^ 1];
            f16* Vn = Vs[cur ^ 1];
            *reinterpret_cast<f16x8*>(&Kn[srow * LSTR + sc8 * 8]) = gk;
            *reinterpret_cast<f16x8*>(&Vn[srow * LSTR + sc8 * 8]) = gv;
        }
        __syncthreads();
    }

    // finalize
    float lt = Lr;
    lt += __shfl_xor(lt, 16);
    lt += __shfl_xor(lt, 32);
    float inv = 1.f / lt;
    size_t row = (size_t)slice * L_SEQ + q0 + l15;
    #pragma unroll
    for (int ei = 0; ei < 4; ++ei) {
        float4 o;
        o.x = oacc[ei][0] * inv; o.y = oacc[ei][1] * inv;
        o.z = oacc[ei][2] * inv; o.w = oacc[ei][3] * inv;
        *reinterpret_cast<float4*>(att + row * E_DIM + ei * 16 + lg * 4) = o;
    }
}

// ---------------------------------------------------------------------------
// InstanceNorm: per-block partial sums (no atomics, no init), then apply
// ---------------------------------------------------------------------------
__global__ __launch_bounds__(256)
void stats_kernel(const float* __restrict__ att, float* __restrict__ parts)
{
    const int slice = blockIdx.x >> 4;
    const int part  = blockIdx.x & 15;
    const int tid = threadIdx.x;
    const size_t base = (size_t)slice * L_SEQ * E_DIM + (size_t)part * 8192;
    float s = 0.f, sq = 0.f;
    #pragma unroll
    for (int it = 0; it < 8; ++it) {
        float4 v = *reinterpret_cast<const float4*>(att + base + (size_t)(it * 256 + tid) * 4);
        s  += v.x + v.y + v.z + v.w;
        sq += v.x * v.x + v.y * v.y + v.z * v.z + v.w * v.w;
    }
    for (int m = 1; m < 64; m <<= 1) {
        s  += __shfl_xor(s,  m);
        sq += __shfl_xor(sq, m);
    }
    __shared__ float red[8];
    const int wid = tid >> 6;
    if ((tid & 63) == 0) { red[wid * 2] = s; red[wid * 2 + 1] = sq; }
    __syncthreads();
    if (tid == 0) {
        parts[slice * 32 + part * 2]     = red[0] + red[2] + red[4] + red[6];
        parts[slice * 32 + part * 2 + 1] = red[1] + red[3] + red[5] + red[7];
    }
}

__global__ __launch_bounds__(256)
void apply_kernel(float* __restrict__ att, const float* __restrict__ parts)
{
    const int i4 = blockIdx.x * 256 + threadIdx.x;
    const size_t fl = (size_t)i4 * 4;
    const int slice = (int)(fl >> 17);
    float S = 0.f, SQ = 0.f;
    #pragma unroll
    for (int p = 0; p < 16; ++p) {
        S  += parts[slice * 32 + p * 2];
        SQ += parts[slice * 32 + p * 2 + 1];
    }
    const float N = (float)(L_SEQ * E_DIM);
    float mean = S / N;
    float var  = SQ / N - mean * mean;
    float inv  = rsqrtf(var + EPSV);
    float4 v = *reinterpret_cast<const float4*>(att + fl);
    float4 o;
    o.x = (v.x - mean) * inv;
    o.y = (v.y - mean) * inv;
    o.z = (v.z - mean) * inv;
    o.w = (v.w - mean) * inv;
    *reinterpret_cast<float4*>(att + fl) = o;
}

// ---------------------------------------------------------------------------
extern "C" void kernel_launch(void* const* d_in, const int* in_sizes, int n_in,
                              void* d_out, int out_size, void* d_ws, size_t ws_size,
                              hipStream_t stream)
{
    const float* info = (const float*)d_in[0];
    const float* Wq   = (const float*)d_in[1];
    const float* bq   = (const float*)d_in[2];
    const float* Wk   = (const float*)d_in[3];
    const float* bk   = (const float*)d_in[4];
    const float* Wv   = (const float*)d_in[5];
    const float* bv   = (const float*)d_in[6];

    // Workspace footprint: 13 MB (known-safe)
    char* ws = (char*)d_ws;
    f16*   Wt    = (f16*)(ws);                       // 294912 B
    float* bias  = (float*)(ws + 294912);            // 768 B
    float* parts = (float*)(ws + 295936);            // 2048 B
    f16*   q16   = (f16*)(ws + 1048576);             // 4 MB
    f16*   k16   = (f16*)(ws + 5242880);             // 4 MB
    f16*   vT    = (f16*)(ws + 9437184);             // 4 MB (end 13 MB)
    float* att   = (float*)d_out;

    prep_kernel<<<36, 256, 0, stream>>>(Wq, bq, Wk, bk, Wv, bv, Wt, bias);
    proj_mfma<<<512, 256, 0, stream>>>(info, Wt, bias, q16, k16, vT);
    attn_mfma<<<dim3(L_SEQ / 128, NSLICE), 512, 0, stream>>>(q16, k16, vT, att);
    stats_kernel<<<256, 256, 0, stream>>>(att, parts);
    apply_kernel<<<2048, 256, 0, stream>>>(att, parts);
}